// Round 4
// baseline (112.173 us; speedup 1.0000x reference)
//
#include <hip/hip_runtime.h>
#include <math.h>

#define TEMP_F 0.07f
#define NCON 20
#define LDIM 512
#define NROWS 32768
#define NSEL 16384
#define MAGIC 0x5F3C9A71u

// ws layout (4-byte units):
// [0 .. 32768)          uint32 flags; flags[r]==MAGIC  =>  row r is referenced
// [32768 .. 65536)      float norm[r]   = ||hg_row r||_2
// [65536 .. 98304)      float dot_sz[r] = <hg_row r, ebar_sz>
// [98304 .. 131072)     float dot_nsz[r]= <hg_row r, ebar_nsz>
//
// Flags need no zeroing: a garbage word that happens to equal MAGIC only
// causes a wasted (unused) row computation — never a wrong answer.

__global__ __launch_bounds__(256) void flag_kernel(const int* __restrict__ sz_idx,
                                                   const int* __restrict__ nsz_idx,
                                                   unsigned* __restrict__ flags) {
    const int i = blockIdx.x * 256 + threadIdx.x;   // 0..32767; blocks 0-63 sz, 64-127 nsz
    const int r = (i < NSEL) ? sz_idx[i] : nsz_idx[i - NSEL];
    flags[r] = MAGIC;
}

__device__ inline float dot4(float4 a, float4 b) {
    return a.x * b.x + a.y * b.y + a.z * b.z + a.w * b.w;
}

// 1024 blocks x 256 threads; wave g owns 8 CONTIGUOUS rows [g*8, g*8+8),
// so the hg stream stays sequential (R3 showed gather order costs ~5 us)
// and the 8 flags are one 32-byte broadcast load.
__global__ __launch_bounds__(256) void rowstats_kernel(const float* __restrict__ hg,
                                                       const float* __restrict__ all_emb,
                                                       const int* __restrict__ Psz,
                                                       const int* __restrict__ Pnsz,
                                                       const unsigned* __restrict__ flags,
                                                       float* __restrict__ ws,
                                                       float* __restrict__ out) {
    __shared__ float ebs[LDIM];
    __shared__ float ebn[LDIM];
    const int t = threadIdx.x;

    // per-block e_bar build (all_emb 40 KB, L2-resident; duplicates in P
    // counted in the mean — matches ref)
    for (int j = t; j < LDIM; j += 256) {
        float s1 = 0.f, s2 = 0.f;
#pragma unroll
        for (int k = 0; k < 5; ++k) {
            s1 += all_emb[Psz[k]  * LDIM + j];
            s2 += all_emb[Pnsz[k] * LDIM + j];
        }
        ebs[j] = s1 * 0.2f;
        ebn[j] = s2 * 0.2f;
    }
    if (blockIdx.x == 0 && t == 0) out[0] = 0.f;   // d_out poisoned each call
    __syncthreads();

    const int lane = t & 63;
    const int w    = t >> 6;

    const float4 es0 = ((const float4*)ebs)[lane * 2];
    const float4 es1 = ((const float4*)ebs)[lane * 2 + 1];
    const float4 en0 = ((const float4*)ebn)[lane * 2];
    const float4 en1 = ((const float4*)ebn)[lane * 2 + 1];

    float* __restrict__ norm_o = ws + NROWS;
    float* __restrict__ dsz_o  = ws + 2 * NROWS;
    float* __restrict__ dnsz_o = ws + 3 * NROWS;

    const int wave = blockIdx.x * 4 + w;        // 0..4095
    const int row0 = wave * 8;

    const uint4 f0 = ((const uint4*)flags)[wave * 2];
    const uint4 f1 = ((const uint4*)flags)[wave * 2 + 1];
    const unsigned fl[8] = {f0.x, f0.y, f0.z, f0.w, f1.x, f1.y, f1.z, f1.w};

#pragma unroll
    for (int k = 0; k < 8; ++k) {
        if (fl[k] != MAGIC) continue;           // wave-uniform skip
        const int row = row0 + k;
        const float4* rp = (const float4*)hg + (size_t)row * (LDIM / 4) + lane * 2;
        const float4 a0 = rp[0];
        const float4 a1 = rp[1];

        float ss   = dot4(a0, a0) + dot4(a1, a1);
        float dsz  = dot4(a0, es0) + dot4(a1, es1);
        float dnsz = dot4(a0, en0) + dot4(a1, en1);

#pragma unroll
        for (int off = 32; off; off >>= 1) {
            ss   += __shfl_xor(ss, off);
            dsz  += __shfl_xor(dsz, off);
            dnsz += __shfl_xor(dnsz, off);
        }
        if (lane == 0) {
            norm_o[row] = sqrtf(ss);
            dsz_o[row]  = dsz;
            dnsz_o[row] = dnsz;
        }
    }
}

// gridDim = (64, 2): 64*256 = 16384 threads per branch, branch = blockIdx.y
__global__ __launch_bounds__(256) void branch_kernel(const float* __restrict__ sim,
                                                     const int* __restrict__ sz_idx,
                                                     const int* __restrict__ nsz_idx,
                                                     const int* __restrict__ Psz,
                                                     const int* __restrict__ Pnsz,
                                                     const float* __restrict__ ws,
                                                     float* __restrict__ out) {
    const int b = blockIdx.y;
    const int* __restrict__ idx = (b == 0) ? sz_idx : nsz_idx;
    const int* __restrict__ P   = (b == 0) ? Psz : Pnsz;

    unsigned mask = (1u << NCON) - 1u;
#pragma unroll
    for (int k = 0; k < 5; ++k) mask &= ~(1u << P[k]);

    const float* __restrict__ norm = ws + NROWS;
    const float* __restrict__ dot  = ws + 2 * NROWS + b * NROWS;

    const int i = blockIdx.x * blockDim.x + threadIdx.x;  // < 16384 exactly
    const int r = idx[i];

    const float4* srow = (const float4*)(sim + (size_t)r * NCON);
    float4 v0 = srow[0], v1 = srow[1], v2 = srow[2], v3 = srow[3], v4 = srow[4];
    float s[NCON] = {v0.x, v0.y, v0.z, v0.w, v1.x, v1.y, v1.z, v1.w,
                     v2.x, v2.y, v2.z, v2.w, v3.x, v3.y, v3.z, v3.w,
                     v4.x, v4.y, v4.z, v4.w};

    const float invT = 1.0f / TEMP_F;
    float den = 0.f;
#pragma unroll
    for (int j = 0; j < NCON; ++j)
        if (mask & (1u << j)) den += expf(s[j] * invT);

    float term = logf(den) - dot[r] * invT / fmaxf(norm[r], 1e-12f);

    __shared__ float red[4];
#pragma unroll
    for (int off = 32; off; off >>= 1) term += __shfl_xor(term, off);
    const int lane = threadIdx.x & 63;
    const int w = threadIdx.x >> 6;
    if (lane == 0) red[w] = term;
    __syncthreads();
    if (threadIdx.x == 0) {
        float bsum = red[0] + red[1] + red[2] + red[3];
        atomicAdd(out, bsum * (1.0f / NSEL));
    }
}

extern "C" void kernel_launch(void* const* d_in, const int* in_sizes, int n_in,
                              void* d_out, int out_size, void* d_ws, size_t ws_size,
                              hipStream_t stream) {
    const float* hg       = (const float*)d_in[0];
    const float* hg_corr  = (const float*)d_in[1];
    const float* all_emb  = (const float*)d_in[2];
    const int*   sz_idx   = (const int*)d_in[3];
    const int*   nsz_idx  = (const int*)d_in[4];
    const int*   Psz      = (const int*)d_in[5];
    const int*   Pnsz     = (const int*)d_in[6];
    float* out = (float*)d_out;
    float* ws  = (float*)d_ws;
    unsigned* flags = (unsigned*)d_ws;

    flag_kernel<<<128, 256, 0, stream>>>(sz_idx, nsz_idx, flags);
    rowstats_kernel<<<1024, 256, 0, stream>>>(hg, all_emb, Psz, Pnsz, flags, ws, out);
    dim3 g(64, 2);
    branch_kernel<<<g, 256, 0, stream>>>(hg_corr, sz_idx, nsz_idx, Psz, Pnsz, ws, out);
}